// Round 10
// baseline (797.554 us; speedup 1.0000x reference)
//
#include <hip/hip_runtime.h>
#include <hip/hip_bf16.h>

#define ND 128
#define EMB 128
#define BATCH 64
#define MM 20
#define NN 500
#define RPAD 8   // rowptr row stride padding so each row is 16-B aligned

typedef short bf16x8 __attribute__((ext_vector_type(8)));
typedef float f32x4 __attribute__((ext_vector_type(4)));

__device__ __forceinline__ float bf2f(unsigned short u) {
    union { unsigned int i; float f; } x; x.i = ((unsigned int)u) << 16; return x.f;
}
__device__ __forceinline__ unsigned short f2bf(float f) {
    union { float f; unsigned int i; } x; x.f = f;
    unsigned int r = x.i + 0x7fffu + ((x.i >> 16) & 1u);
    return (unsigned short)(r >> 16);
}
__device__ __forceinline__ float2 bfpair(unsigned int p) {
    union { unsigned int i; float f; } a, b;
    a.i = p << 16; b.i = p & 0xffff0000u;
    return make_float2(a.f, b.f);
}

// ---------------- CSR build (fused over the 3 edge lists) ----------------
struct EdgePtrs { const int* e[3]; };

__global__ void edge_hist3(EdgePtrs ep, int* __restrict__ cnt, int E, int N) {
    int li = blockIdx.y;
    const int* dst = ep.e[li] + E;
    int e = blockIdx.x * blockDim.x + threadIdx.x;
    if (e < E) atomicAdd(&cnt[(size_t)li * N + dst[e]], 1);
}

// vectorized + wave-shuffle exclusive scan; grid = 3 blocks x 1024 threads.
__global__ void exscan3(const int* __restrict__ cnt, int* __restrict__ rowptr, int n) {
    __shared__ int wsum[16];
    __shared__ int woff[16];
    int li = blockIdx.x;
    const int4* c4 = (const int4*)(cnt + (size_t)li * n);
    int* rp = rowptr + (size_t)li * (n + RPAD);
    int t = threadIdx.x;
    int lane = t & 63, wid = t >> 6;
    int n4 = n >> 2;  // n % 4 == 0

    int4 v[8];
    int s = 0;
#pragma unroll
    for (int i = 0; i < 8; ++i) {
        int idx = t * 8 + i;
        if (idx < n4) v[i] = c4[idx];
        else { v[i].x = v[i].y = v[i].z = v[i].w = 0; }
    }
#pragma unroll
    for (int i = 0; i < 8; ++i) s += v[i].x + v[i].y + v[i].z + v[i].w;

    int ps = s;
#pragma unroll
    for (int d = 1; d < 64; d <<= 1) {
        int u = __shfl_up(ps, d, 64);
        if (lane >= d) ps += u;
    }
    if (lane == 63) wsum[wid] = ps;
    __syncthreads();
    if (t == 0) {
        int r = 0;
        for (int i = 0; i < 16; ++i) { woff[i] = r; r += wsum[i]; }
    }
    __syncthreads();
    int run = woff[wid] + ps - s;
    int4* rp4 = (int4*)rp;
#pragma unroll
    for (int i = 0; i < 8; ++i) {
        int idx = t * 8 + i;
        if (idx < n4) {
            int4 o;
            o.x = run; run += v[i].x;
            o.y = run; run += v[i].y;
            o.z = run; run += v[i].z;
            o.w = run; run += v[i].w;
            rp4[idx] = o;
        }
    }
    if (t == (n - 1) / 32) rp[n] = run;
}

// countdown scatter: plain store through the cache. 45 us measured; window variants
// (R3: 24 blocks, R9: 240 blocks) were both slower -> this is the local optimum.
__global__ void edge_scatter3(EdgePtrs ep, const int* __restrict__ rowptr, int* __restrict__ cnt,
                              int* __restrict__ col, int E, int N) {
    int li = blockIdx.y;
    const int* src = ep.e[li];
    const int* dst = src + E;
    const int* rp = rowptr + (size_t)li * (N + RPAD);
    int e = blockIdx.x * blockDim.x + threadIdx.x;
    if (e < E) {
        int d = dst[e];
        int p = atomicSub(&cnt[(size_t)li * N + d], 1) - 1;
        col[(size_t)li * E + rp[d] + p] = src[e];
    }
}

// ---------------- fused weight build (all 4 weight sets in one launch) ----------------
struct WcPtrs {
    const float* lw[4]; const float* lb[4]; const float* aw[4]; const float* ab[4];
    unsigned short* Whi[4]; unsigned short* Wlo[4]; float* Bf[4];
};

__global__ void make_wc4(WcPtrs p) {
    int set = blockIdx.y;
    const float* lw = p.lw[set]; const float* lb = p.lb[set];
    const float* aw = p.aw[set]; const float* ab = p.ab[set];
    int n = blockIdx.x;   // 0..383
    int e = threadIdx.x;  // 0..127
    float w;
    if (n < 128) {
        w = lw[n * 128 + e];
    } else if (n < 256) {
        int ni = n - 128; float s = 0.f;
        for (int k = 0; k < 128; ++k) s += aw[ni * 256 + k] * lw[k * 128 + e];
        w = s;
    } else {
        int nj = n - 256; float s = 0.f;
        for (int k = 0; k < 128; ++k) s += aw[nj * 256 + 128 + k] * lw[k * 128 + e];
        w = s;
    }
    unsigned short hi = f2bf(w);
    p.Whi[set][n * 128 + e] = hi;
    p.Wlo[set][n * 128 + e] = f2bf(w - bf2f(hi));
    if (e == 0) {
        float b;
        if (n < 128) b = lb[n];
        else if (n < 256) {
            int ni = n - 128; float s = ab[ni];
            for (int k = 0; k < 128; ++k) s += aw[ni * 256 + k] * lb[k];
            b = s;
        } else {
            int nj = n - 256; float s = 0.f;
            for (int k = 0; k < 128; ++k) s += aw[nj * 256 + 128 + k] * lb[k];
            b = s;
        }
        p.Bf[set][n] = b;
    }
}

// ---------------- fused GEMM into packed hu ----------------
// R10: LOW-VGPR restructure. The old kernel preloaded all 32 weight fragments
// (128 VGPRs) -> ~200 VGPR/thread -> ONE 6-wave block per CU (~1.5 waves/SIMD),
// zero latency hiding -- which is why R4/R6/R7 micro-opts were all neutral.
// Now weight fragments are loaded per-nt-iteration from L2 (192 KB, hot;
// #pragma unroll 1 stops the compiler re-hoisting them). Target VGPR ~100 ->
// 2-3 blocks/CU. Keeps R6's double-buffered X staging + one barrier per tile.
// Split-precision: acc += Xhi*Whi + Xlo*Whi + Xhi*Wlo  (~fp32 exact).
__launch_bounds__(384)
__global__ void lin_fused(const float* __restrict__ X,
                          const unsigned short* __restrict__ Whi,
                          const unsigned short* __restrict__ Wlo,
                          const float* __restrict__ bias,
                          void* __restrict__ hu, int M) {
    __shared__ __align__(16) unsigned short sxh[2][16][136];
    __shared__ __align__(16) unsigned short sxl[2][16][136];
    const int tid = threadIdx.x;
    const int slab = tid >> 6;  // 0..5: 0,1=h  2,3=ui  4,5=uj
    const int lane = tid & 63;
    const int r16 = lane & 15;
    const int quad = lane >> 4;
    const int srow = tid >> 4;        // staging row (tid<256)
    const int scol = (tid & 15) * 8;  // staging col

    unsigned short* hu16 = (unsigned short*)hu;  // row stride 512 shorts
    float* huf = (float*)hu;                     // row stride 256 floats

    const unsigned short* Wh = Whi + (size_t)slab * 64 * 128;
    const unsigned short* Wl = Wlo + (size_t)slab * 64 * 128;
    float bv[4];
#pragma unroll
    for (int nt = 0; nt < 4; ++nt) bv[nt] = bias[slab * 64 + nt * 16 + r16];

    const int mt_count = M >> 4;
    const int G = gridDim.x;
    const int mt0 = blockIdx.x;

    // prologue: stage tile mt0 into buf 0
    {
        float v[8];
        if (tid < 256) {
            const float* xp = X + (size_t)(mt0 * 16 + srow) * 128 + scol;
            float4 v0 = *(const float4*)xp;
            float4 v1 = *(const float4*)(xp + 4);
            v[0] = v0.x; v[1] = v0.y; v[2] = v0.z; v[3] = v0.w;
            v[4] = v1.x; v[5] = v1.y; v[6] = v1.z; v[7] = v1.w;
            unsigned int hh[4], ll[4];
#pragma unroll
            for (int j = 0; j < 4; ++j) {
                unsigned short h0 = f2bf(v[2 * j]);
                unsigned short h1 = f2bf(v[2 * j + 1]);
                unsigned short l0 = f2bf(v[2 * j] - bf2f(h0));
                unsigned short l1 = f2bf(v[2 * j + 1] - bf2f(h1));
                hh[j] = (unsigned int)h0 | ((unsigned int)h1 << 16);
                ll[j] = (unsigned int)l0 | ((unsigned int)l1 << 16);
            }
            *(uint4*)&sxh[0][srow][scol] = make_uint4(hh[0], hh[1], hh[2], hh[3]);
            *(uint4*)&sxl[0][srow][scol] = make_uint4(ll[0], ll[1], ll[2], ll[3]);
        }
    }
    __syncthreads();

    int cur = 0;
    for (int mt = mt0; mt < mt_count; mt += G) {
        const int nxt = mt + G;
        const bool has = nxt < mt_count;

        // early-issue next tile's global loads (latency hides under MFMA below)
        float v[8];
        if (has && tid < 256) {
            const float* xp = X + (size_t)(nxt * 16 + srow) * 128 + scol;
            float4 v0 = *(const float4*)xp;
            float4 v1 = *(const float4*)(xp + 4);
            v[0] = v0.x; v[1] = v0.y; v[2] = v0.z; v[3] = v0.w;
            v[4] = v1.x; v[5] = v1.y; v[6] = v1.z; v[7] = v1.w;
        }

        bf16x8 ah[4], al[4];
#pragma unroll
        for (int ks = 0; ks < 4; ++ks) {
            ah[ks] = *(const bf16x8*)&sxh[cur][r16][ks * 32 + quad * 8];
            al[ks] = *(const bf16x8*)&sxl[cur][r16][ks * 32 + quad * 8];
        }

        // per-nt weight loads (L2-hot), NOT preloaded: keeps VGPR low
#pragma unroll 1
        for (int nt = 0; nt < 4; ++nt) {
            bf16x8 wh[4], wl[4];
#pragma unroll
            for (int ks = 0; ks < 4; ++ks) {
                wh[ks] = *(const bf16x8*)(Wh + (nt * 16 + r16) * 128 + ks * 32 + quad * 8);
                wl[ks] = *(const bf16x8*)(Wl + (nt * 16 + r16) * 128 + ks * 32 + quad * 8);
            }
            f32x4 acc = {bv[nt], bv[nt], bv[nt], bv[nt]};
#pragma unroll
            for (int ks = 0; ks < 4; ++ks) {
                acc = __builtin_amdgcn_mfma_f32_16x16x32_bf16(ah[ks], wh[ks], acc, 0, 0, 0);
                acc = __builtin_amdgcn_mfma_f32_16x16x32_bf16(al[ks], wh[ks], acc, 0, 0, 0);
                acc = __builtin_amdgcn_mfma_f32_16x16x32_bf16(ah[ks], wl[ks], acc, 0, 0, 0);
            }
            int col = slab * 64 + nt * 16 + r16;
#pragma unroll
            for (int r = 0; r < 4; ++r) {
                size_t row = (size_t)(mt * 16 + quad * 4 + r);
                if (slab < 2) {
                    int c = col;
                    hu16[row * 512 + ((c & ~1) << 1) + (c & 1)] = f2bf(acc[r]);
                } else if (slab < 4) {
                    int c = col - 128;
                    huf[row * 256 + 128 + c] = acc[r];
                } else {
                    int c = col - 256;
                    hu16[row * 512 + ((c & ~1) << 1) + 2 + (c & 1)] = f2bf(acc[r]);
                }
            }
        }

        // convert + write next tile into the other buffer
        if (has && tid < 256) {
            unsigned int hh[4], ll[4];
#pragma unroll
            for (int j = 0; j < 4; ++j) {
                unsigned short h0 = f2bf(v[2 * j]);
                unsigned short h1 = f2bf(v[2 * j + 1]);
                unsigned short l0 = f2bf(v[2 * j] - bf2f(h0));
                unsigned short l1 = f2bf(v[2 * j + 1] - bf2f(h1));
                hh[j] = (unsigned int)h0 | ((unsigned int)h1 << 16);
                ll[j] = (unsigned int)l0 | ((unsigned int)l1 << 16);
            }
            *(uint4*)&sxh[cur ^ 1][srow][scol] = make_uint4(hh[0], hh[1], hh[2], hh[3]);
            *(uint4*)&sxl[cur ^ 1][srow][scol] = make_uint4(ll[0], ll[1], ll[2], ll[3]);
        }
        __syncthreads();
        cur ^= 1;
    }
}

// ---------------- GAT aggregation: one wave per dst node, online softmax ----------------
__global__ void gat_agg(const void* __restrict__ hu,
                        const int* __restrict__ rowptr, const int* __restrict__ col,
                        const float* __restrict__ resid,
                        float* __restrict__ out, int N) {
    int wid = (int)((blockIdx.x * blockDim.x + threadIdx.x) >> 6);
    if (wid >= N) return;
    int lane = threadIdx.x & 63;
    const uint2* P = (const uint2*)hu;    // row stride 128 uint2
    const float2* U = (const float2*)hu;  // row stride 128 float2, ui at +64

    float2 uiv = U[(size_t)wid * 128 + 64 + lane];
    uint2 sp = P[(size_t)wid * 128 + lane];
    float2 hs = bfpair(sp.x);
    float2 ujs = bfpair(sp.y);

    float a0 = uiv.x + ujs.x; a0 = a0 > 0.f ? a0 : 0.2f * a0;
    float a1 = uiv.y + ujs.y; a1 = a1 > 0.f ? a1 : 0.2f * a1;
    float m0 = a0, m1 = a1, l0 = 1.f, l1 = 1.f;
    float acc0 = hs.x, acc1 = hs.y;

#define AGG_STEP(pk)                                                      \
    {                                                                     \
        float2 hj = bfpair(pk.x);                                         \
        float2 uj = bfpair(pk.y);                                         \
        float b0 = uiv.x + uj.x; b0 = b0 > 0.f ? b0 : 0.2f * b0;          \
        float b1 = uiv.y + uj.y; b1 = b1 > 0.f ? b1 : 0.2f * b1;          \
        float n0 = fmaxf(m0, b0), n1 = fmaxf(m1, b1);                     \
        float s0 = __expf(m0 - n0), s1 = __expf(m1 - n1);                 \
        float p0 = __expf(b0 - n0), p1 = __expf(b1 - n1);                 \
        l0 = l0 * s0 + p0;            l1 = l1 * s1 + p1;                  \
        acc0 = acc0 * s0 + hj.x * p0; acc1 = acc1 * s1 + hj.y * p1;       \
        m0 = n0; m1 = n1;                                                 \
    }

    int e = rowptr[wid], end = rowptr[wid + 1];
    for (; e + 8 <= end; e += 8) {
        int s0i = col[e],     s1i = col[e + 1], s2i = col[e + 2], s3i = col[e + 3];
        int s4i = col[e + 4], s5i = col[e + 5], s6i = col[e + 6], s7i = col[e + 7];
        uint2 p0 = P[(size_t)s0i * 128 + lane];
        uint2 p1 = P[(size_t)s1i * 128 + lane];
        uint2 p2 = P[(size_t)s2i * 128 + lane];
        uint2 p3 = P[(size_t)s3i * 128 + lane];
        uint2 p4 = P[(size_t)s4i * 128 + lane];
        uint2 p5 = P[(size_t)s5i * 128 + lane];
        uint2 p6 = P[(size_t)s6i * 128 + lane];
        uint2 p7 = P[(size_t)s7i * 128 + lane];
        AGG_STEP(p0);
        AGG_STEP(p1);
        AGG_STEP(p2);
        AGG_STEP(p3);
        AGG_STEP(p4);
        AGG_STEP(p5);
        AGG_STEP(p6);
        AGG_STEP(p7);
    }
    for (; e + 4 <= end; e += 4) {
        int sA = col[e], sB = col[e + 1], sC = col[e + 2], sD = col[e + 3];
        uint2 pA = P[(size_t)sA * 128 + lane];
        uint2 pB = P[(size_t)sB * 128 + lane];
        uint2 pC = P[(size_t)sC * 128 + lane];
        uint2 pD = P[(size_t)sD * 128 + lane];
        AGG_STEP(pA);
        AGG_STEP(pB);
        AGG_STEP(pC);
        AGG_STEP(pD);
    }
    for (; e < end; ++e) {
        int sA = col[e];
        uint2 pA = P[(size_t)sA * 128 + lane];
        AGG_STEP(pA);
    }
#undef AGG_STEP

    float o0 = acc0 / (l0 + 1e-16f);
    float o1 = acc1 / (l1 + 1e-16f);
    if (resid) {
        float2 rv = ((const float2*)resid)[(size_t)wid * 64 + lane];
        o0 += rv.x; o1 += rv.y;
    }
    ((float2*)out)[(size_t)wid * 64 + lane] = make_float2(o0, o1);
}

// ---------------- GRU (fp32, one block of 128 per batch row) ----------------
__global__ void gru_kernel(const float* __restrict__ st_, const float* __restrict__ in_,
                           const float* __restrict__ win,
                           const float* __restrict__ wz, const float* __restrict__ bz,
                           const float* __restrict__ wr, const float* __restrict__ br,
                           const float* __restrict__ wh, const float* __restrict__ bh,
                           float* __restrict__ out) {
    __shared__ float sst[ND], sib[EMB], si[ND], srs[ND];
    int b = blockIdx.x, d = threadIdx.x;
    float s = 0.f;
    for (int m = 0; m < MM; ++m) s += in_[((size_t)b * MM + m) * EMB + d];
    sib[d] = s * (1.0f / MM);
    sst[d] = st_[b * ND + d];
    __syncthreads();
    float iv = 0.f;
    for (int e = 0; e < EMB; ++e) iv += sib[e] * win[d * EMB + e];
    si[d] = iv;
    __syncthreads();
    float za = bz[d], ra = br[d];
    for (int e = 0; e < ND; ++e) {
        za += sst[e] * wz[d * 2 * ND + e] + si[e] * wz[d * 2 * ND + ND + e];
        ra += sst[e] * wr[d * 2 * ND + e] + si[e] * wr[d * 2 * ND + ND + e];
    }
    float z = 1.f / (1.f + __expf(-za));
    float r = 1.f / (1.f + __expf(-ra));
    srs[d] = r * sst[d];
    __syncthreads();
    float ha = bh[d];
    for (int e = 0; e < ND; ++e)
        ha += srs[e] * wh[d * 2 * ND + e] + si[e] * wh[d * 2 * ND + ND + e];
    float hc = tanhf(ha);
    out[b * ND + d] = (1.f - z) * sst[d] + z * hc;
}

// ---------------- heads phase 1: wave-per-node dots + elu outputs + staged scores ----------------
__global__ void heads_dots(const float* __restrict__ gx,
                           const float* __restrict__ pw_,
                           const float* __restrict__ mw_, const float* __restrict__ mb_,
                           const float* __restrict__ sw_, const float* __restrict__ sbias_,
                           float* __restrict__ scores, float* __restrict__ out) {
    int t = blockIdx.x;
    int lane = threadIdx.x & 63;
    int b = blockIdx.y * 4 + (threadIdx.x >> 6);
    const float2* g2 = (const float2*)gx;
    float2 pwv = ((const float2*)pw_)[lane];
    float2 mwv = ((const float2*)mw_)[lane];
    float2 swv = ((const float2*)sw_)[lane];
    int node = b * NN + 1 + t;
    float2 xv = g2[(size_t)node * 64 + lane];
    float dp = xv.x * pwv.x + xv.y * pwv.y;
    float dm = xv.x * mwv.x + xv.y * mwv.y;
    float ds = xv.x * swv.x + xv.y * swv.y;
    for (int off = 32; off; off >>= 1) {
        dp += __shfl_xor(dp, off);
        dm += __shfl_xor(dm, off);
        ds += __shfl_xor(ds, off);
    }
    if (lane == 0) {
        scores[(size_t)b * (NN - 1) + t] = dp;  // pb cancels in softmax
        float av = dm + mb_[0]; av = av > 0.f ? av : (__expf(av) - 1.f);
        float bv = fabsf(ds + sbias_[0]);       // elu(|x|) == |x|
        float* oA = out + BATCH * ND + (size_t)BATCH * (NN - 1);
        float* oB = oA + (size_t)BATCH * (NN - 1);
        oA[(size_t)b * (NN - 1) + t] = av + 2.f;
        oB[(size_t)b * (NN - 1) + t] = bv + 2.f;
    }
}

// ---------------- heads phase 2: softmax over 499 per batch row ----------------
__global__ void heads_softmax(const float* __restrict__ scores, float* __restrict__ out) {
    __shared__ float scs[NN - 1], red[256];
    int b = blockIdx.x, tid = threadIdx.x;
    float mx = -1e30f;
    for (int t = tid; t < NN - 1; t += 256) { float v = scores[(size_t)b * (NN - 1) + t]; scs[t] = v; mx = fmaxf(mx, v); }
    red[tid] = mx; __syncthreads();
    for (int off = 128; off; off >>= 1) { if (tid < off) red[tid] = fmaxf(red[tid], red[tid + off]); __syncthreads(); }
    mx = red[0]; __syncthreads();
    float sum = 0.f;
    for (int t = tid; t < NN - 1; t += 256) { float e = __expf(scs[t] - mx); scs[t] = e; sum += e; }
    red[tid] = sum; __syncthreads();
    for (int off = 128; off; off >>= 1) { if (tid < off) red[tid] += red[tid + off]; __syncthreads(); }
    float inv = 1.0f / red[0];
    float* oP = out + BATCH * ND + (size_t)b * (NN - 1);
    for (int t = tid; t < NN - 1; t += 256) oP[t] = scs[t] * inv;
}

extern "C" void kernel_launch(void* const* d_in, const int* in_sizes, int n_in,
                              void* d_out, int out_size, void* d_ws, size_t ws_size,
                              hipStream_t stream) {
    const float* state_ = (const float*)d_in[0];
    const float* input_ = (const float*)d_in[1];
    const float* x      = (const float*)d_in[2];
    const int* e_n  = (const int*)d_in[3];
    const int* e_r0 = (const int*)d_in[4];
    const int* e_r1 = (const int*)d_in[5];
    const float* win = (const float*)d_in[7];
    const float* wz  = (const float*)d_in[8];
    const float* bz  = (const float*)d_in[9];
    const float* wr  = (const float*)d_in[10];
    const float* br  = (const float*)d_in[11];
    const float* wh  = (const float*)d_in[12];
    const float* bh  = (const float*)d_in[13];
    const float* pw = (const float*)d_in[30];
    const float* mw = (const float*)d_in[32];
    const float* mb = (const float*)d_in[33];
    const float* sw = (const float*)d_in[34];
    const float* sb = (const float*)d_in[35];
    float* out = (float*)d_out;

    const int E = in_sizes[3] / 2;    // 256000
    const int N = in_sizes[2] / EMB;  // 32000

    char* w = (char*)d_ws;
    auto alloc = [&](size_t bytes) { char* p = w; w += (bytes + 255) & ~(size_t)255; return p; };
    int* rpbase = (int*)alloc(3 * (size_t)(N + RPAD) * sizeof(int));
    int* colbase = (int*)alloc(3 * (size_t)E * sizeof(int));
    int* tmp = (int*)alloc(3 * (size_t)N * sizeof(int));
    unsigned short* Whi[4]; unsigned short* Wlo[4]; float* Bf[4];
    for (int i = 0; i < 4; ++i) {
        Whi[i] = (unsigned short*)alloc(384 * 128 * 2);
        Wlo[i] = (unsigned short*)alloc(384 * 128 * 2);
        Bf[i]  = (float*)alloc(384 * 4);
    }
    void* hu = (void*)alloc((size_t)N * 1024);   // packed bf16 h|uj + fp32 ui
    float* ga = (float*)alloc((size_t)N * 128 * 4);
    float* gb = (float*)alloc((size_t)N * 128 * 4);
    float* gc = (float*)alloc((size_t)N * 128 * 4);
    float* scores = (float*)alloc((size_t)BATCH * (NN - 1) * 4);

    EdgePtrs ep; ep.e[0] = e_n; ep.e[1] = e_r0; ep.e[2] = e_r1;

    hipMemsetAsync(tmp, 0, 3 * (size_t)N * sizeof(int), stream);
    edge_hist3<<<dim3((E + 255) / 256, 3), 256, 0, stream>>>(ep, tmp, E, N);
    exscan3<<<3, 1024, 0, stream>>>(tmp, rpbase, N);
    edge_scatter3<<<dim3((E + 255) / 256, 3), 256, 0, stream>>>(ep, rpbase, tmp, colbase, E, N);

    WcPtrs wp;
    wp.lw[0] = (const float*)d_in[14]; wp.lb[0] = (const float*)d_in[15];
    wp.aw[0] = (const float*)d_in[16]; wp.ab[0] = (const float*)d_in[17];
    wp.lw[1] = (const float*)d_in[18]; wp.lb[1] = (const float*)d_in[19];
    wp.aw[1] = (const float*)d_in[20]; wp.ab[1] = (const float*)d_in[21];
    wp.lw[2] = (const float*)d_in[22]; wp.lb[2] = (const float*)d_in[23];
    wp.aw[2] = (const float*)d_in[24]; wp.ab[2] = (const float*)d_in[25];
    wp.lw[3] = (const float*)d_in[26]; wp.lb[3] = (const float*)d_in[27];
    wp.aw[3] = (const float*)d_in[28]; wp.ab[3] = (const float*)d_in[29];
    for (int i = 0; i < 4; ++i) { wp.Whi[i] = Whi[i]; wp.Wlo[i] = Wlo[i]; wp.Bf[i] = Bf[i]; }
    make_wc4<<<dim3(384, 4), 128, 0, stream>>>(wp);

    gru_kernel<<<BATCH, ND, 0, stream>>>(state_, input_, win, wz, bz, wr, br, wh, bh, out);

    auto conv = [&](const float* in, int csr_i, int wi, const float* resid, float* o) {
        lin_fused<<<512, 384, 0, stream>>>(in, Whi[wi], Wlo[wi], Bf[wi], hu, N);
        gat_agg<<<(N * 64) / 256, 256, 0, stream>>>(hu, rpbase + (size_t)csr_i * (N + RPAD),
                                                    colbase + (size_t)csr_i * E, resid, o, N);
    };

    conv(x,  0, 0, nullptr, ga);  // g0 (e_n)
    conv(ga, 2, 1, nullptr, gb);  // g1 (e_r1)
    conv(gb, 2, 1, nullptr, gc);  // g2 (e_r1, g1 weights)
    conv(gc, 0, 3, ga,      gb);  // g3 = conv(g2, e_n, gn) + g0
    conv(gb, 1, 2, nullptr, gc);  // g4 (e_r0, g2 weights)
    conv(gc, 1, 2, nullptr, ga);  // g5 (e_r0, g2 weights)
    conv(ga, 0, 3, gb,      gc);  // gx = conv(g5, e_n, gn) + g3

    heads_dots<<<dim3(NN - 1, 16), 256, 0, stream>>>(gc, pw, mw, mb, sw, sb, scores, out);
    heads_softmax<<<BATCH, 256, 0, stream>>>(scores, out);
}

// Round 11
// 613.019 us; speedup vs baseline: 1.3010x; 1.3010x over previous
//
#include <hip/hip_runtime.h>
#include <hip/hip_bf16.h>

#define ND 128
#define EMB 128
#define BATCH 64
#define MM 20
#define NN 500
#define RPAD 8   // rowptr row stride padding so each row is 16-B aligned

typedef short bf16x8 __attribute__((ext_vector_type(8)));
typedef float f32x4 __attribute__((ext_vector_type(4)));

__device__ __forceinline__ float bf2f(unsigned short u) {
    union { unsigned int i; float f; } x; x.i = ((unsigned int)u) << 16; return x.f;
}
__device__ __forceinline__ unsigned short f2bf(float f) {
    union { float f; unsigned int i; } x; x.f = f;
    unsigned int r = x.i + 0x7fffu + ((x.i >> 16) & 1u);
    return (unsigned short)(r >> 16);
}
__device__ __forceinline__ float2 bfpair(unsigned int p) {
    union { unsigned int i; float f; } a, b;
    a.i = p << 16; b.i = p & 0xffff0000u;
    return make_float2(a.f, b.f);
}

// ---------------- CSR build (fused over the 3 edge lists) ----------------
struct EdgePtrs { const int* e[3]; };

__global__ void edge_hist3(EdgePtrs ep, int* __restrict__ cnt, int E, int N) {
    int li = blockIdx.y;
    const int* dst = ep.e[li] + E;
    int e = blockIdx.x * blockDim.x + threadIdx.x;
    if (e < E) atomicAdd(&cnt[(size_t)li * N + dst[e]], 1);
}

// vectorized + wave-shuffle exclusive scan; grid = 3 blocks x 1024 threads.
__global__ void exscan3(const int* __restrict__ cnt, int* __restrict__ rowptr, int n) {
    __shared__ int wsum[16];
    __shared__ int woff[16];
    int li = blockIdx.x;
    const int4* c4 = (const int4*)(cnt + (size_t)li * n);
    int* rp = rowptr + (size_t)li * (n + RPAD);
    int t = threadIdx.x;
    int lane = t & 63, wid = t >> 6;
    int n4 = n >> 2;  // n % 4 == 0

    int4 v[8];
    int s = 0;
#pragma unroll
    for (int i = 0; i < 8; ++i) {
        int idx = t * 8 + i;
        if (idx < n4) v[i] = c4[idx];
        else { v[i].x = v[i].y = v[i].z = v[i].w = 0; }
    }
#pragma unroll
    for (int i = 0; i < 8; ++i) s += v[i].x + v[i].y + v[i].z + v[i].w;

    int ps = s;
#pragma unroll
    for (int d = 1; d < 64; d <<= 1) {
        int u = __shfl_up(ps, d, 64);
        if (lane >= d) ps += u;
    }
    if (lane == 63) wsum[wid] = ps;
    __syncthreads();
    if (t == 0) {
        int r = 0;
        for (int i = 0; i < 16; ++i) { woff[i] = r; r += wsum[i]; }
    }
    __syncthreads();
    int run = woff[wid] + ps - s;
    int4* rp4 = (int4*)rp;
#pragma unroll
    for (int i = 0; i < 8; ++i) {
        int idx = t * 8 + i;
        if (idx < n4) {
            int4 o;
            o.x = run; run += v[i].x;
            o.y = run; run += v[i].y;
            o.z = run; run += v[i].z;
            o.w = run; run += v[i].w;
            rp4[idx] = o;
        }
    }
    if (t == (n - 1) / 32) rp[n] = run;
}

// countdown scatter: plain store through the cache. 45 us measured; window variants
// (R3: 24 blocks, R9: 240 blocks) were both slower -> this is the local optimum.
__global__ void edge_scatter3(EdgePtrs ep, const int* __restrict__ rowptr, int* __restrict__ cnt,
                              int* __restrict__ col, int E, int N) {
    int li = blockIdx.y;
    const int* src = ep.e[li];
    const int* dst = src + E;
    const int* rp = rowptr + (size_t)li * (N + RPAD);
    int e = blockIdx.x * blockDim.x + threadIdx.x;
    if (e < E) {
        int d = dst[e];
        int p = atomicSub(&cnt[(size_t)li * N + d], 1) - 1;
        col[(size_t)li * E + rp[d] + p] = src[e];
    }
}

// ---------------- fused weight build (all 4 weight sets in one launch) ----------------
struct WcPtrs {
    const float* lw[4]; const float* lb[4]; const float* aw[4]; const float* ab[4];
    unsigned short* Whi[4]; unsigned short* Wlo[4]; float* Bf[4];
};

__global__ void make_wc4(WcPtrs p) {
    int set = blockIdx.y;
    const float* lw = p.lw[set]; const float* lb = p.lb[set];
    const float* aw = p.aw[set]; const float* ab = p.ab[set];
    int n = blockIdx.x;   // 0..383
    int e = threadIdx.x;  // 0..127
    float w;
    if (n < 128) {
        w = lw[n * 128 + e];
    } else if (n < 256) {
        int ni = n - 128; float s = 0.f;
        for (int k = 0; k < 128; ++k) s += aw[ni * 256 + k] * lw[k * 128 + e];
        w = s;
    } else {
        int nj = n - 256; float s = 0.f;
        for (int k = 0; k < 128; ++k) s += aw[nj * 256 + 128 + k] * lw[k * 128 + e];
        w = s;
    }
    unsigned short hi = f2bf(w);
    p.Whi[set][n * 128 + e] = hi;
    p.Wlo[set][n * 128 + e] = f2bf(w - bf2f(hi));
    if (e == 0) {
        float b;
        if (n < 128) b = lb[n];
        else if (n < 256) {
            int ni = n - 128; float s = ab[ni];
            for (int k = 0; k < 128; ++k) s += aw[ni * 256 + k] * lb[k];
            b = s;
        } else {
            int nj = n - 256; float s = 0.f;
            for (int k = 0; k < 128; ++k) s += aw[nj * 256 + 128 + k] * lb[k];
            b = s;
        }
        p.Bf[set][n] = b;
    }
}

// ---------------- fused GEMM into packed hu ----------------
// R11: 12-wave blocks, 32 output cols per wave. Weights stay PRELOADED (R10's
// per-iteration L2 loads inserted 4 serial ~300cy latencies/tile: 31->54 us),
// but per-thread weight VGPR halves (128->64, total ~130 with launch_bounds(768,3)
// -> 3 waves/SIMD) and per-tile wave parallelism doubles (12 waves co-compute).
// Keeps R6's double-buffered X staging + one barrier per tile + direct stores.
// Split-precision: acc += Xhi*Whi + Xlo*Whi + Xhi*Wlo  (~fp32 exact).
__launch_bounds__(768, 3)
__global__ void lin_fused(const float* __restrict__ X,
                          const unsigned short* __restrict__ Whi,
                          const unsigned short* __restrict__ Wlo,
                          const float* __restrict__ bias,
                          void* __restrict__ hu, int M) {
    __shared__ __align__(16) unsigned short sxh[2][16][136];
    __shared__ __align__(16) unsigned short sxl[2][16][136];
    const int tid = threadIdx.x;
    const int wave = tid >> 6;  // 0..11: cols [wave*32, wave*32+32)
    const int lane = tid & 63;
    const int r16 = lane & 15;
    const int quad = lane >> 4;
    const int srow = tid >> 4;        // staging row (tid<256)
    const int scol = (tid & 15) * 8;  // staging col

    unsigned short* hu16 = (unsigned short*)hu;  // row stride 512 shorts
    float* huf = (float*)hu;                     // row stride 256 floats

    // preload this wave's 32 weight rows (hi+lo): 16 bf16x8 = 64 VGPRs
    bf16x8 wh[2][4], wl[2][4];
#pragma unroll
    for (int nt = 0; nt < 2; ++nt)
#pragma unroll
        for (int ks = 0; ks < 4; ++ks) {
            size_t wrow = (size_t)(wave * 32 + nt * 16 + r16) * 128 + ks * 32 + quad * 8;
            wh[nt][ks] = *(const bf16x8*)(Whi + wrow);
            wl[nt][ks] = *(const bf16x8*)(Wlo + wrow);
        }
    float bv[2];
#pragma unroll
    for (int nt = 0; nt < 2; ++nt) bv[nt] = bias[wave * 32 + nt * 16 + r16];

    const int mt_count = M >> 4;
    const int G = gridDim.x;
    const int mt0 = blockIdx.x;

    // prologue: stage tile mt0 into buf 0
    {
        float v[8];
        if (tid < 256) {
            const float* xp = X + (size_t)(mt0 * 16 + srow) * 128 + scol;
            float4 v0 = *(const float4*)xp;
            float4 v1 = *(const float4*)(xp + 4);
            v[0] = v0.x; v[1] = v0.y; v[2] = v0.z; v[3] = v0.w;
            v[4] = v1.x; v[5] = v1.y; v[6] = v1.z; v[7] = v1.w;
            unsigned int hh[4], ll[4];
#pragma unroll
            for (int j = 0; j < 4; ++j) {
                unsigned short h0 = f2bf(v[2 * j]);
                unsigned short h1 = f2bf(v[2 * j + 1]);
                unsigned short l0 = f2bf(v[2 * j] - bf2f(h0));
                unsigned short l1 = f2bf(v[2 * j + 1] - bf2f(h1));
                hh[j] = (unsigned int)h0 | ((unsigned int)h1 << 16);
                ll[j] = (unsigned int)l0 | ((unsigned int)l1 << 16);
            }
            *(uint4*)&sxh[0][srow][scol] = make_uint4(hh[0], hh[1], hh[2], hh[3]);
            *(uint4*)&sxl[0][srow][scol] = make_uint4(ll[0], ll[1], ll[2], ll[3]);
        }
    }
    __syncthreads();

    int cur = 0;
    for (int mt = mt0; mt < mt_count; mt += G) {
        const int nxt = mt + G;
        const bool has = nxt < mt_count;

        // early-issue next tile's global loads (latency hides under MFMA below)
        float v[8];
        if (has && tid < 256) {
            const float* xp = X + (size_t)(nxt * 16 + srow) * 128 + scol;
            float4 v0 = *(const float4*)xp;
            float4 v1 = *(const float4*)(xp + 4);
            v[0] = v0.x; v[1] = v0.y; v[2] = v0.z; v[3] = v0.w;
            v[4] = v1.x; v[5] = v1.y; v[6] = v1.z; v[7] = v1.w;
        }

        bf16x8 ah[4], al[4];
#pragma unroll
        for (int ks = 0; ks < 4; ++ks) {
            ah[ks] = *(const bf16x8*)&sxh[cur][r16][ks * 32 + quad * 8];
            al[ks] = *(const bf16x8*)&sxl[cur][r16][ks * 32 + quad * 8];
        }

#pragma unroll
        for (int nt = 0; nt < 2; ++nt) {
            f32x4 acc = {bv[nt], bv[nt], bv[nt], bv[nt]};
#pragma unroll
            for (int ks = 0; ks < 4; ++ks) {
                acc = __builtin_amdgcn_mfma_f32_16x16x32_bf16(ah[ks], wh[nt][ks], acc, 0, 0, 0);
                acc = __builtin_amdgcn_mfma_f32_16x16x32_bf16(al[ks], wh[nt][ks], acc, 0, 0, 0);
                acc = __builtin_amdgcn_mfma_f32_16x16x32_bf16(ah[ks], wl[nt][ks], acc, 0, 0, 0);
            }
            int cc = wave * 32 + nt * 16 + r16;
#pragma unroll
            for (int r = 0; r < 4; ++r) {
                size_t row = (size_t)(mt * 16 + quad * 4 + r);
                if (cc < 128) {
                    hu16[row * 512 + ((cc & ~1) << 1) + (cc & 1)] = f2bf(acc[r]);
                } else if (cc < 256) {
                    int c = cc - 128;
                    huf[row * 256 + 128 + c] = acc[r];
                } else {
                    int c = cc - 256;
                    hu16[row * 512 + ((c & ~1) << 1) + 2 + (c & 1)] = f2bf(acc[r]);
                }
            }
        }

        // convert + write next tile into the other buffer
        if (has && tid < 256) {
            unsigned int hh[4], ll[4];
#pragma unroll
            for (int j = 0; j < 4; ++j) {
                unsigned short h0 = f2bf(v[2 * j]);
                unsigned short h1 = f2bf(v[2 * j + 1]);
                unsigned short l0 = f2bf(v[2 * j] - bf2f(h0));
                unsigned short l1 = f2bf(v[2 * j + 1] - bf2f(h1));
                hh[j] = (unsigned int)h0 | ((unsigned int)h1 << 16);
                ll[j] = (unsigned int)l0 | ((unsigned int)l1 << 16);
            }
            *(uint4*)&sxh[cur ^ 1][srow][scol] = make_uint4(hh[0], hh[1], hh[2], hh[3]);
            *(uint4*)&sxl[cur ^ 1][srow][scol] = make_uint4(ll[0], ll[1], ll[2], ll[3]);
        }
        __syncthreads();
        cur ^= 1;
    }
}

// ---------------- GAT aggregation: one wave per dst node, online softmax ----------------
__global__ void gat_agg(const void* __restrict__ hu,
                        const int* __restrict__ rowptr, const int* __restrict__ col,
                        const float* __restrict__ resid,
                        float* __restrict__ out, int N) {
    int wid = (int)((blockIdx.x * blockDim.x + threadIdx.x) >> 6);
    if (wid >= N) return;
    int lane = threadIdx.x & 63;
    const uint2* P = (const uint2*)hu;    // row stride 128 uint2
    const float2* U = (const float2*)hu;  // row stride 128 float2, ui at +64

    float2 uiv = U[(size_t)wid * 128 + 64 + lane];
    uint2 sp = P[(size_t)wid * 128 + lane];
    float2 hs = bfpair(sp.x);
    float2 ujs = bfpair(sp.y);

    float a0 = uiv.x + ujs.x; a0 = a0 > 0.f ? a0 : 0.2f * a0;
    float a1 = uiv.y + ujs.y; a1 = a1 > 0.f ? a1 : 0.2f * a1;
    float m0 = a0, m1 = a1, l0 = 1.f, l1 = 1.f;
    float acc0 = hs.x, acc1 = hs.y;

#define AGG_STEP(pk)                                                      \
    {                                                                     \
        float2 hj = bfpair(pk.x);                                         \
        float2 uj = bfpair(pk.y);                                         \
        float b0 = uiv.x + uj.x; b0 = b0 > 0.f ? b0 : 0.2f * b0;          \
        float b1 = uiv.y + uj.y; b1 = b1 > 0.f ? b1 : 0.2f * b1;          \
        float n0 = fmaxf(m0, b0), n1 = fmaxf(m1, b1);                     \
        float s0 = __expf(m0 - n0), s1 = __expf(m1 - n1);                 \
        float p0 = __expf(b0 - n0), p1 = __expf(b1 - n1);                 \
        l0 = l0 * s0 + p0;            l1 = l1 * s1 + p1;                  \
        acc0 = acc0 * s0 + hj.x * p0; acc1 = acc1 * s1 + hj.y * p1;       \
        m0 = n0; m1 = n1;                                                 \
    }

    int e = rowptr[wid], end = rowptr[wid + 1];
    for (; e + 8 <= end; e += 8) {
        int s0i = col[e],     s1i = col[e + 1], s2i = col[e + 2], s3i = col[e + 3];
        int s4i = col[e + 4], s5i = col[e + 5], s6i = col[e + 6], s7i = col[e + 7];
        uint2 p0 = P[(size_t)s0i * 128 + lane];
        uint2 p1 = P[(size_t)s1i * 128 + lane];
        uint2 p2 = P[(size_t)s2i * 128 + lane];
        uint2 p3 = P[(size_t)s3i * 128 + lane];
        uint2 p4 = P[(size_t)s4i * 128 + lane];
        uint2 p5 = P[(size_t)s5i * 128 + lane];
        uint2 p6 = P[(size_t)s6i * 128 + lane];
        uint2 p7 = P[(size_t)s7i * 128 + lane];
        AGG_STEP(p0);
        AGG_STEP(p1);
        AGG_STEP(p2);
        AGG_STEP(p3);
        AGG_STEP(p4);
        AGG_STEP(p5);
        AGG_STEP(p6);
        AGG_STEP(p7);
    }
    for (; e + 4 <= end; e += 4) {
        int sA = col[e], sB = col[e + 1], sC = col[e + 2], sD = col[e + 3];
        uint2 pA = P[(size_t)sA * 128 + lane];
        uint2 pB = P[(size_t)sB * 128 + lane];
        uint2 pC = P[(size_t)sC * 128 + lane];
        uint2 pD = P[(size_t)sD * 128 + lane];
        AGG_STEP(pA);
        AGG_STEP(pB);
        AGG_STEP(pC);
        AGG_STEP(pD);
    }
    for (; e < end; ++e) {
        int sA = col[e];
        uint2 pA = P[(size_t)sA * 128 + lane];
        AGG_STEP(pA);
    }
#undef AGG_STEP

    float o0 = acc0 / (l0 + 1e-16f);
    float o1 = acc1 / (l1 + 1e-16f);
    if (resid) {
        float2 rv = ((const float2*)resid)[(size_t)wid * 64 + lane];
        o0 += rv.x; o1 += rv.y;
    }
    ((float2*)out)[(size_t)wid * 64 + lane] = make_float2(o0, o1);
}

// ---------------- GRU (fp32, one block of 128 per batch row) ----------------
__global__ void gru_kernel(const float* __restrict__ st_, const float* __restrict__ in_,
                           const float* __restrict__ win,
                           const float* __restrict__ wz, const float* __restrict__ bz,
                           const float* __restrict__ wr, const float* __restrict__ br,
                           const float* __restrict__ wh, const float* __restrict__ bh,
                           float* __restrict__ out) {
    __shared__ float sst[ND], sib[EMB], si[ND], srs[ND];
    int b = blockIdx.x, d = threadIdx.x;
    float s = 0.f;
    for (int m = 0; m < MM; ++m) s += in_[((size_t)b * MM + m) * EMB + d];
    sib[d] = s * (1.0f / MM);
    sst[d] = st_[b * ND + d];
    __syncthreads();
    float iv = 0.f;
    for (int e = 0; e < EMB; ++e) iv += sib[e] * win[d * EMB + e];
    si[d] = iv;
    __syncthreads();
    float za = bz[d], ra = br[d];
    for (int e = 0; e < ND; ++e) {
        za += sst[e] * wz[d * 2 * ND + e] + si[e] * wz[d * 2 * ND + ND + e];
        ra += sst[e] * wr[d * 2 * ND + e] + si[e] * wr[d * 2 * ND + ND + e];
    }
    float z = 1.f / (1.f + __expf(-za));
    float r = 1.f / (1.f + __expf(-ra));
    srs[d] = r * sst[d];
    __syncthreads();
    float ha = bh[d];
    for (int e = 0; e < ND; ++e)
        ha += srs[e] * wh[d * 2 * ND + e] + si[e] * wh[d * 2 * ND + ND + e];
    float hc = tanhf(ha);
    out[b * ND + d] = (1.f - z) * sst[d] + z * hc;
}

// ---------------- heads phase 1: wave-per-node dots + elu outputs + staged scores ----------------
__global__ void heads_dots(const float* __restrict__ gx,
                           const float* __restrict__ pw_,
                           const float* __restrict__ mw_, const float* __restrict__ mb_,
                           const float* __restrict__ sw_, const float* __restrict__ sbias_,
                           float* __restrict__ scores, float* __restrict__ out) {
    int t = blockIdx.x;
    int lane = threadIdx.x & 63;
    int b = blockIdx.y * 4 + (threadIdx.x >> 6);
    const float2* g2 = (const float2*)gx;
    float2 pwv = ((const float2*)pw_)[lane];
    float2 mwv = ((const float2*)mw_)[lane];
    float2 swv = ((const float2*)sw_)[lane];
    int node = b * NN + 1 + t;
    float2 xv = g2[(size_t)node * 64 + lane];
    float dp = xv.x * pwv.x + xv.y * pwv.y;
    float dm = xv.x * mwv.x + xv.y * mwv.y;
    float ds = xv.x * swv.x + xv.y * swv.y;
    for (int off = 32; off; off >>= 1) {
        dp += __shfl_xor(dp, off);
        dm += __shfl_xor(dm, off);
        ds += __shfl_xor(ds, off);
    }
    if (lane == 0) {
        scores[(size_t)b * (NN - 1) + t] = dp;  // pb cancels in softmax
        float av = dm + mb_[0]; av = av > 0.f ? av : (__expf(av) - 1.f);
        float bv = fabsf(ds + sbias_[0]);       // elu(|x|) == |x|
        float* oA = out + BATCH * ND + (size_t)BATCH * (NN - 1);
        float* oB = oA + (size_t)BATCH * (NN - 1);
        oA[(size_t)b * (NN - 1) + t] = av + 2.f;
        oB[(size_t)b * (NN - 1) + t] = bv + 2.f;
    }
}

// ---------------- heads phase 2: softmax over 499 per batch row ----------------
__global__ void heads_softmax(const float* __restrict__ scores, float* __restrict__ out) {
    __shared__ float scs[NN - 1], red[256];
    int b = blockIdx.x, tid = threadIdx.x;
    float mx = -1e30f;
    for (int t = tid; t < NN - 1; t += 256) { float v = scores[(size_t)b * (NN - 1) + t]; scs[t] = v; mx = fmaxf(mx, v); }
    red[tid] = mx; __syncthreads();
    for (int off = 128; off; off >>= 1) { if (tid < off) red[tid] = fmaxf(red[tid], red[tid + off]); __syncthreads(); }
    mx = red[0]; __syncthreads();
    float sum = 0.f;
    for (int t = tid; t < NN - 1; t += 256) { float e = __expf(scs[t] - mx); scs[t] = e; sum += e; }
    red[tid] = sum; __syncthreads();
    for (int off = 128; off; off >>= 1) { if (tid < off) red[tid] += red[tid + off]; __syncthreads(); }
    float inv = 1.0f / red[0];
    float* oP = out + BATCH * ND + (size_t)b * (NN - 1);
    for (int t = tid; t < NN - 1; t += 256) oP[t] = scs[t] * inv;
}

extern "C" void kernel_launch(void* const* d_in, const int* in_sizes, int n_in,
                              void* d_out, int out_size, void* d_ws, size_t ws_size,
                              hipStream_t stream) {
    const float* state_ = (const float*)d_in[0];
    const float* input_ = (const float*)d_in[1];
    const float* x      = (const float*)d_in[2];
    const int* e_n  = (const int*)d_in[3];
    const int* e_r0 = (const int*)d_in[4];
    const int* e_r1 = (const int*)d_in[5];
    const float* win = (const float*)d_in[7];
    const float* wz  = (const float*)d_in[8];
    const float* bz  = (const float*)d_in[9];
    const float* wr  = (const float*)d_in[10];
    const float* br  = (const float*)d_in[11];
    const float* wh  = (const float*)d_in[12];
    const float* bh  = (const float*)d_in[13];
    const float* pw = (const float*)d_in[30];
    const float* mw = (const float*)d_in[32];
    const float* mb = (const float*)d_in[33];
    const float* sw = (const float*)d_in[34];
    const float* sb = (const float*)d_in[35];
    float* out = (float*)d_out;

    const int E = in_sizes[3] / 2;    // 256000
    const int N = in_sizes[2] / EMB;  // 32000

    char* w = (char*)d_ws;
    auto alloc = [&](size_t bytes) { char* p = w; w += (bytes + 255) & ~(size_t)255; return p; };
    int* rpbase = (int*)alloc(3 * (size_t)(N + RPAD) * sizeof(int));
    int* colbase = (int*)alloc(3 * (size_t)E * sizeof(int));
    int* tmp = (int*)alloc(3 * (size_t)N * sizeof(int));
    unsigned short* Whi[4]; unsigned short* Wlo[4]; float* Bf[4];
    for (int i = 0; i < 4; ++i) {
        Whi[i] = (unsigned short*)alloc(384 * 128 * 2);
        Wlo[i] = (unsigned short*)alloc(384 * 128 * 2);
        Bf[i]  = (float*)alloc(384 * 4);
    }
    void* hu = (void*)alloc((size_t)N * 1024);   // packed bf16 h|uj + fp32 ui
    float* ga = (float*)alloc((size_t)N * 128 * 4);
    float* gb = (float*)alloc((size_t)N * 128 * 4);
    float* gc = (float*)alloc((size_t)N * 128 * 4);
    float* scores = (float*)alloc((size_t)BATCH * (NN - 1) * 4);

    EdgePtrs ep; ep.e[0] = e_n; ep.e[1] = e_r0; ep.e[2] = e_r1;

    hipMemsetAsync(tmp, 0, 3 * (size_t)N * sizeof(int), stream);
    edge_hist3<<<dim3((E + 255) / 256, 3), 256, 0, stream>>>(ep, tmp, E, N);
    exscan3<<<3, 1024, 0, stream>>>(tmp, rpbase, N);
    edge_scatter3<<<dim3((E + 255) / 256, 3), 256, 0, stream>>>(ep, rpbase, tmp, colbase, E, N);

    WcPtrs wp;
    wp.lw[0] = (const float*)d_in[14]; wp.lb[0] = (const float*)d_in[15];
    wp.aw[0] = (const float*)d_in[16]; wp.ab[0] = (const float*)d_in[17];
    wp.lw[1] = (const float*)d_in[18]; wp.lb[1] = (const float*)d_in[19];
    wp.aw[1] = (const float*)d_in[20]; wp.ab[1] = (const float*)d_in[21];
    wp.lw[2] = (const float*)d_in[22]; wp.lb[2] = (const float*)d_in[23];
    wp.aw[2] = (const float*)d_in[24]; wp.ab[2] = (const float*)d_in[25];
    wp.lw[3] = (const float*)d_in[26]; wp.lb[3] = (const float*)d_in[27];
    wp.aw[3] = (const float*)d_in[28]; wp.ab[3] = (const float*)d_in[29];
    for (int i = 0; i < 4; ++i) { wp.Whi[i] = Whi[i]; wp.Wlo[i] = Wlo[i]; wp.Bf[i] = Bf[i]; }
    make_wc4<<<dim3(384, 4), 128, 0, stream>>>(wp);

    gru_kernel<<<BATCH, ND, 0, stream>>>(state_, input_, win, wz, bz, wr, br, wh, bh, out);

    auto conv = [&](const float* in, int csr_i, int wi, const float* resid, float* o) {
        lin_fused<<<512, 768, 0, stream>>>(in, Whi[wi], Wlo[wi], Bf[wi], hu, N);
        gat_agg<<<(N * 64) / 256, 256, 0, stream>>>(hu, rpbase + (size_t)csr_i * (N + RPAD),
                                                    colbase + (size_t)csr_i * E, resid, o, N);
    };

    conv(x,  0, 0, nullptr, ga);  // g0 (e_n)
    conv(ga, 2, 1, nullptr, gb);  // g1 (e_r1)
    conv(gb, 2, 1, nullptr, gc);  // g2 (e_r1, g1 weights)
    conv(gc, 0, 3, ga,      gb);  // g3 = conv(g2, e_n, gn) + g0
    conv(gb, 1, 2, nullptr, gc);  // g4 (e_r0, g2 weights)
    conv(gc, 1, 2, nullptr, ga);  // g5 (e_r0, g2 weights)
    conv(ga, 0, 3, gb,      gc);  // gx = conv(g5, e_n, gn) + g3

    heads_dots<<<dim3(NN - 1, 16), 256, 0, stream>>>(gc, pw, mw, mb, sw, sb, scores, out);
    heads_softmax<<<BATCH, 256, 0, stream>>>(scores, out);
}